// Round 10
// baseline (868.279 us; speedup 1.0000x reference)
//
#include <hip/hip_runtime.h>
#include <hip/hip_bf16.h>
#include <stdint.h>

typedef __attribute__((ext_vector_type(8))) short short8;
typedef __attribute__((ext_vector_type(4))) float f32x4;
typedef __attribute__((ext_vector_type(4))) float float4v;
typedef __attribute__((ext_vector_type(4))) int int4v;

#define MDIM 8192
#define NDIM 11008
#define KDIM 4096
#define BKI  64                /* i8 K-tile (bytes per LDS row) */
#define NTI  (KDIM / BKI)      /* 64 K-tiles */
#define NBMI (MDIM / 128)      /* 64 */
#define NBNI (NDIM / 128)      /* 86 */

// ws layout (bytes)
#define XQ_OFF  0ull
#define WQ_OFF  ((size_t)MDIM * KDIM)                 /* 33554432 */
#define SXT_OFF (WQ_OFF + (size_t)NDIM * KDIM)        /* + 45088768 */
#define SWT_OFF (SXT_OFF + 16ull * MDIM * 4)          /* + 524288 */
#define WS_NEED (SWT_OFF + 16ull * NDIM * 4)          /* ~79.9 MB */

static __device__ __forceinline__ unsigned short f2bf(float f) {
  union { float f; unsigned int u; } v;
  v.f = f;
  unsigned int r = v.u + 0x7FFFu + ((v.u >> 16) & 1u);
  return (unsigned short)(r >> 16);
}

#define GLDS16(g, l) __builtin_amdgcn_global_load_lds(                         \
    (const __attribute__((address_space(1))) void*)(g),                        \
    (__attribute__((address_space(3))) void*)(l), 16, 0, 0)

// ---------------- pass 1 (fused): x -> int8 groups  |  qweight -> int8 pack --
__global__ __launch_bounds__(256) void prep_all(
    const float* __restrict__ x, char* __restrict__ xq, float* __restrict__ sxT,
    const int* __restrict__ qw, const float* __restrict__ scale,
    char* __restrict__ wq, float* __restrict__ swT) {
  const int t = threadIdx.x;
  if (blockIdx.x < MDIM) {
    const int row = blockIdx.x;
    const float* p = x + (size_t)row * KDIM + t * 16;
    float4v v[4];
#pragma unroll
    for (int c = 0; c < 4; ++c) v[c] = *(const float4v*)(p + c * 4);
    float amax = 0.f;
#pragma unroll
    for (int c = 0; c < 4; ++c)
#pragma unroll
      for (int e = 0; e < 4; ++e) amax = fmaxf(amax, fabsf(v[c][e]));
#pragma unroll
    for (int d = 1; d < 16; d <<= 1) amax = fmaxf(amax, __shfl_xor(amax, d));
    amax = fmaxf(amax, 1e-20f);
    if ((t & 15) == 0)
      sxT[(size_t)(t >> 4) * MDIM + row] = amax * (1.0f / 127.0f);
    const float inv = 127.0f / amax;
    int4v o;
#pragma unroll
    for (int c = 0; c < 4; ++c) {
      unsigned int r = 0;
#pragma unroll
      for (int e = 0; e < 4; ++e) {
        int q = __float2int_rn(v[c][e] * inv);
        r |= ((unsigned int)(q & 255)) << (8 * e);
      }
      o[c] = (int)r;
    }
    *(int4v*)(xq + (size_t)row * KDIM + t * 16) = o;
  } else {
    const int row = blockIdx.x - MDIM;
    const int* p = qw + (size_t)row * KDIM + t * 16;
    int4v v[4];
#pragma unroll
    for (int c = 0; c < 4; ++c) v[c] = *(const int4v*)(p + c * 4);
    int4v o;
#pragma unroll
    for (int c = 0; c < 4; ++c) {
      unsigned int r = 0;
#pragma unroll
      for (int e = 0; e < 4; ++e) r |= ((unsigned int)(v[c][e] & 255)) << (8 * e);
      o[c] = (int)r;
    }
    *(int4v*)(wq + (size_t)row * KDIM + t * 16) = o;
    if ((t & 15) == 0)
      swT[(size_t)(t >> 4) * NDIM + row] = 1.0f / scale[(size_t)row * 16 + (t >> 4)];
  }
}

// ---------------- pass 2: 128x128 i8 GEMM; A via LDS, B direct-to-register --
// LDS-read traffic halved vs r9 (B fragments are 16B/lane -> straight from L2
// into VGPRs, double-buffered distance-1). Counted vmcnt with PINNED issue
// order per tile: [A-stage(t+3) x2 GLDS, B-load(t+1) x4]; steady vmcnt(6)
// drains exactly {A(t+2) stage, B(t) regs}. Tail drains 6->4->4->0.
__global__ __launch_bounds__(256, 2) void gemm_i8(
    const char* __restrict__ xq, const char* __restrict__ wq,
    const float* __restrict__ sxT, const float* __restrict__ swT,
    const float* __restrict__ bias, float* __restrict__ out)
{
  __shared__ unsigned char lds[49152];
  unsigned char* ldsA = lds;              // [4][8192]: 128 rows x 64B
  float* sxl = (float*)(lds + 32768);     // [16][128] row scales
  float* swl = (float*)(lds + 40960);     // [16][128] col inv-scales

  const int t = threadIdx.x;
  const int lane = t & 63;
  const int w = t >> 6;        // wave 0..3
  const int wr = w >> 1;       // 0..1  (A 64-row half)
  const int wc = w & 1;        // 0..1  (B 64-col half)
  const int lh = lane >> 4;    // 0..3
  const int l15 = lane & 15;

  // XCD-bijective swizzle: 5504 = 8 * 688
  const int bid = blockIdx.x;
  const int swz = (bid & 7) * (NBMI * NBNI / 8) + (bid >> 3);
  const int bm = swz / NBNI;
  const int bn = swz % NBNI;

  // A read swizzle: row r holds logical granule g at phys g ^ f(r),
  // f(r) = (r&3)^((r>>2)&3)
  const int f15 = (l15 & 3) ^ (l15 >> 2);
  const int rdGran = (lh ^ f15) << 4;
  // A staging: linear LDS dest (lane*16) <- pre-swizzled global source
  const int srow16 = lane >> 2;
  const int q = (lane & 3) ^ (srow16 & 3) ^ ((srow16 >> 2) & 3);
  const size_t srcOff = (size_t)srow16 * KDIM + q * 16;
  const char* aS = xq + ((size_t)(bm * 128 + w * 32)) * KDIM + srcOff;

  // B direct: lane (l15, lh) reads B[col wc*64+n*16+l15][k lh*16..+15]
  const char* bq = wq + (size_t)(bn * 128 + wc * 64 + l15) * KDIM + lh * 16;

  // ---- bias: load early and pin (keep it out of the counted vm queue) ----
  float bias_v[4];
#pragma unroll
  for (int n = 0; n < 4; ++n) {
    bias_v[n] = bias[bn * 128 + wc * 64 + n * 16 + l15];
    asm volatile("" :: "v"(bias_v[n]));
  }

  // ---- stage scale tables into LDS ----
  {
    const int tg = t >> 4;
    const int tc = (t & 15) * 8;
    float4v a0 = *(const float4v*)(sxT + (size_t)tg * MDIM + bm * 128 + tc);
    float4v a1 = *(const float4v*)(sxT + (size_t)tg * MDIM + bm * 128 + tc + 4);
    float4v b0 = *(const float4v*)(swT + (size_t)tg * NDIM + bn * 128 + tc);
    float4v b1 = *(const float4v*)(swT + (size_t)tg * NDIM + bn * 128 + tc + 4);
    *(float4v*)(sxl + tg * 128 + tc)     = a0;
    *(float4v*)(sxl + tg * 128 + tc + 4) = a1;
    *(float4v*)(swl + tg * 128 + tc)     = b0;
    *(float4v*)(swl + tg * 128 + tc + 4) = b1;
  }
  __syncthreads();   // drains vmcnt to 0 (compiler emits vmcnt(0) here)

  f32x4 accf[4][4];
  int4v acci[4][4];
#pragma unroll
  for (int m = 0; m < 4; ++m)
#pragma unroll
    for (int n = 0; n < 4; ++n) {
      accf[m][n] = (f32x4){0.f, 0.f, 0.f, 0.f};
      acci[m][n] = (int4v){0, 0, 0, 0};
    }

#define STAGE_A(buf, kt) {                                                     \
  GLDS16(aS + (kt) * BKI,             ldsA + (buf) * 8192 + w * 2048);         \
  GLDS16(aS + 16 * KDIM + (kt) * BKI, ldsA + (buf) * 8192 + w * 2048 + 1024); }

#define BLOAD(BARR, kt) {                                                      \
  _Pragma("unroll")                                                            \
  for (int n = 0; n < 4; ++n)                                                  \
    BARR[n] = *(const int4v*)(bq + (size_t)n * 16 * KDIM + (kt) * BKI); }

#define RD_A(buf, m) (*(const int4v*)(ldsA + (buf) * 8192 + wr * 4096 +        \
                      (m) * 1024 + l15 * 64 + rdGran))

#define VMW(N) asm volatile("s_waitcnt vmcnt(" N ")" ::: "memory");

// tile t: issue [A-stage(t+3), B-load(t+1)] (order pinned), ds_read A(t),
// counted wait, 16 MFMA, optional fixup, barrier.
#define TILE(abuf, kt, BCUR, BNXT, DOSTAGEA, DOLOADB, WAITN, DOFIX, DOBAR) {   \
  if (DOSTAGEA) STAGE_A(((abuf) + 3) & 3, (kt) + 3);                           \
  __builtin_amdgcn_sched_barrier(0);                                           \
  if (DOLOADB) BLOAD(BNXT, (kt) + 1);                                          \
  __builtin_amdgcn_sched_barrier(0);                                           \
  int4v a[4];                                                                  \
  _Pragma("unroll")                                                            \
  for (int i = 0; i < 4; ++i) a[i] = RD_A(abuf, i);                            \
  float4v sxv[4]; float swv[4];                                                \
  if (DOFIX) {                                                                 \
    const int g = (kt) >> 2;                                                   \
    _Pragma("unroll")                                                          \
    for (int m = 0; m < 4; ++m)                                                \
      sxv[m] = *(const float4v*)(sxl + g * 128 + wr * 64 + m * 16 + lh * 4);   \
    _Pragma("unroll")                                                          \
    for (int n = 0; n < 4; ++n)                                                \
      swv[n] = swl[g * 128 + wc * 64 + n * 16 + l15];                          \
  }                                                                            \
  VMW(WAITN)                                                                   \
  __builtin_amdgcn_s_setprio(1);                                               \
  _Pragma("unroll")                                                            \
  for (int m = 0; m < 4; ++m)                                                  \
    _Pragma("unroll")                                                          \
    for (int n = 0; n < 4; ++n)                                                \
      acci[m][n] = __builtin_amdgcn_mfma_i32_16x16x64_i8(a[m], BCUR[n],        \
                                                         acci[m][n], 0, 0, 0); \
  __builtin_amdgcn_s_setprio(0);                                               \
  if (DOFIX) {                                                                 \
    _Pragma("unroll")                                                          \
    for (int m = 0; m < 4; ++m)                                                \
      _Pragma("unroll")                                                        \
      for (int n = 0; n < 4; ++n) {                                            \
        _Pragma("unroll")                                                      \
        for (int j = 0; j < 4; ++j)                                            \
          accf[m][n][j] += (float)acci[m][n][j] * (sxv[m][j] * swv[n]);        \
        acci[m][n] = (int4v){0, 0, 0, 0};                                      \
      }                                                                        \
  }                                                                            \
  if (DOBAR) __builtin_amdgcn_s_barrier(); }

  int4v B0f[4], B1f[4];

  // ---- prologue: A0,A1,A2 staged (6 GLDS), B0 loaded (4) ----
  STAGE_A(0, 0);
  STAGE_A(1, 1);
  STAGE_A(2, 2);
  __builtin_amdgcn_sched_barrier(0);
  BLOAD(B0f, 0);
  __builtin_amdgcn_sched_barrier(0);
  VMW("8")                      // drain A(0); leaves A1,A2,B0 = 8
  __builtin_amdgcn_s_barrier();

  for (int kt = 0; kt < NTI - 4; kt += 4) {
    TILE(0, kt,     B0f, B1f, 1, 1, "6", 0, 1)
    TILE(1, kt + 1, B1f, B0f, 1, 1, "6", 0, 1)
    TILE(2, kt + 2, B0f, B1f, 1, 1, "6", 0, 1)
    TILE(3, kt + 3, B1f, B0f, 1, 1, "6", 1, 1)
  }
  // tail: t60 steady; t61 no A-stage; t62 last B; t63 drain-all
  TILE(0, NTI - 4, B0f, B1f, 1, 1, "6", 0, 1)
  TILE(1, NTI - 3, B1f, B0f, 0, 1, "4", 0, 1)
  TILE(2, NTI - 2, B0f, B1f, 0, 1, "4", 0, 1)
  TILE(3, NTI - 1, B1f, B0f, 0, 0, "0", 1, 0)

  // epilogue: bias + fp32 store (C/D map: col=lane&15, row=(lane>>4)*4+j)
#pragma unroll
  for (int m = 0; m < 4; ++m) {
    const int row0 = bm * 128 + wr * 64 + m * 16 + lh * 4;
#pragma unroll
    for (int n = 0; n < 4; ++n) {
      const int col = bn * 128 + wc * 64 + n * 16 + l15;
      const float bv_ = bias_v[n];
#pragma unroll
      for (int j = 0; j < 4; ++j)
        out[(size_t)(row0 + j) * NDIM + col] = accf[m][n][j] + bv_;
    }
  }
#undef TILE
#undef VMW
#undef RD_A
#undef BLOAD
#undef STAGE_A
}

// ---------------- fallback: fused single-pass (round-1 kernel) ----------------
__global__ __launch_bounds__(256, 2) void clinear_fused(
    const float* __restrict__ x,
    const int* __restrict__ qw,
    const float* __restrict__ scale,
    const float* __restrict__ bias,
    float* __restrict__ out)
{
  __shared__ unsigned char ldsA[128 * 64 * 2];
  __shared__ unsigned char ldsB[128 * 64 * 2];

  const int t = threadIdx.x;
  const int lane = t & 63;
  const int wave = t >> 6;
  const int wr = wave >> 1;
  const int wc = wave & 1;

  const int NBN = NDIM / 128;
  const int bid = blockIdx.x;
  const int cpx = ((MDIM / 128) * NBN) >> 3;
  const int swz = (bid & 7) * cpx + (bid >> 3);
  const int bm = swz / NBN;
  const int bn = swz % NBN;

  const int srow = t >> 1;
  const int shalf = t & 1;
  const float* aptr = x  + (size_t)(bm * 128 + srow) * KDIM + shalf * 32;
  const int*   bptr = qw + (size_t)(bn * 128 + srow) * KDIM + shalf * 32;
  const float* sptr = scale + (size_t)(bn * 128 + srow) * (KDIM / 256);
  const int arx = srow & 7;

  f32x4 acc[4][4];
#pragma unroll
  for (int i = 0; i < 4; ++i)
#pragma unroll
    for (int j = 0; j < 4; ++j)
      acc[i][j] = (f32x4){0.f, 0.f, 0.f, 0.f};

  float bias_v[4];
#pragma unroll
  for (int n = 0; n < 4; ++n)
    bias_v[n] = bias[bn * 128 + wc * 64 + n * 16 + (lane & 15)];

  for (int kt = 0; kt < KDIM / 64; ++kt) {
    const int k0 = kt * 64;
    float4v av[8];
    int4v   bv[8];
#pragma unroll
    for (int j = 0; j < 8; ++j) av[j] = *(const float4v*)(aptr + k0 + 4 * j);
#pragma unroll
    for (int j = 0; j < 8; ++j) bv[j] = *(const int4v*)(bptr + k0 + 4 * j);
    const float inv = 1.0f / sptr[k0 >> 8];

    __syncthreads();
#pragma unroll
    for (int c = 0; c < 4; ++c) {
      short8 pa, pb;
#pragma unroll
      for (int e = 0; e < 8; ++e) {
        const int v = c * 8 + e;
        pa[e] = (short)f2bf(av[v >> 2][v & 3]);
        pb[e] = (short)f2bf((float)bv[v >> 2][v & 3] * inv);
      }
      const int cc = shalf * 4 + c;
      *(short8*)(ldsA + srow * 128 + ((cc ^ arx) << 4)) = pa;
      *(short8*)(ldsB + srow * 128 + ((cc ^ arx) << 4)) = pb;
    }
    __syncthreads();

    short8 af[4][2], bfr[4][2];
#pragma unroll
    for (int m = 0; m < 4; ++m) {
      const int r = wr * 64 + m * 16 + (lane & 15);
      const int rx = r & 7;
#pragma unroll
      for (int ks = 0; ks < 2; ++ks) {
        const int ch = ks * 4 + (lane >> 4);
        af[m][ks] = *(const short8*)(ldsA + r * 128 + ((ch ^ rx) << 4));
      }
    }
#pragma unroll
    for (int n = 0; n < 4; ++n) {
      const int r = wc * 64 + n * 16 + (lane & 15);
      const int rx = r & 7;
#pragma unroll
      for (int ks = 0; ks < 2; ++ks) {
        const int ch = ks * 4 + (lane >> 4);
        bfr[n][ks] = *(const short8*)(ldsB + r * 128 + ((ch ^ rx) << 4));
      }
    }
#pragma unroll
    for (int ks = 0; ks < 2; ++ks)
#pragma unroll
      for (int m = 0; m < 4; ++m)
#pragma unroll
        for (int n = 0; n < 4; ++n)
          acc[m][n] = __builtin_amdgcn_mfma_f32_16x16x32_bf16(
              af[m][ks], bfr[n][ks], acc[m][n], 0, 0, 0);
  }

#pragma unroll
  for (int m = 0; m < 4; ++m) {
    const int row0 = bm * 128 + wr * 64 + m * 16 + (lane >> 4) * 4;
#pragma unroll
    for (int n = 0; n < 4; ++n) {
      const int col = bn * 128 + wc * 64 + n * 16 + (lane & 15);
      const float bv_ = bias_v[n];
#pragma unroll
      for (int j = 0; j < 4; ++j)
        out[(size_t)(row0 + j) * NDIM + col] = acc[m][n][j] + bv_;
    }
  }
}

extern "C" void kernel_launch(void* const* d_in, const int* in_sizes, int n_in,
                              void* d_out, int out_size, void* d_ws, size_t ws_size,
                              hipStream_t stream) {
  const float* x     = (const float*)d_in[0];
  const int*   qw    = (const int*)d_in[1];
  const float* scale = (const float*)d_in[2];
  const float* bias  = (const float*)d_in[3];
  float* out = (float*)d_out;

  if (ws_size >= WS_NEED) {
    char*  xqb = (char*)d_ws + XQ_OFF;
    char*  wqb = (char*)d_ws + WQ_OFF;
    float* sxT = (float*)((char*)d_ws + SXT_OFF);
    float* swT = (float*)((char*)d_ws + SWT_OFF);
    hipLaunchKernelGGL(prep_all, dim3(MDIM + NDIM), dim3(256), 0, stream,
                       x, xqb, sxT, qw, scale, wqb, swT);
    hipLaunchKernelGGL(gemm_i8, dim3(NBMI * NBNI), dim3(256), 0, stream,
                       xqb, wqb, sxT, swT, bias, out);
  } else {
    hipLaunchKernelGGL(clinear_fused, dim3((MDIM / 128) * (NDIM / 128)), dim3(256),
                       0, stream, x, qw, scale, bias, out);
  }
}

// Round 11
// 629.403 us; speedup vs baseline: 1.3795x; 1.3795x over previous
//
#include <hip/hip_runtime.h>
#include <hip/hip_bf16.h>
#include <stdint.h>

typedef __attribute__((ext_vector_type(8))) short short8;
typedef __attribute__((ext_vector_type(4))) float f32x4;
typedef __attribute__((ext_vector_type(4))) float float4v;
typedef __attribute__((ext_vector_type(4))) int int4v;

#define MDIM 8192
#define NDIM 11008
#define KDIM 4096
#define BKI  64                /* i8 K-tile */
#define NTI  (KDIM / BKI)      /* 64 K-tiles */
#define NBMI (MDIM / 128)      /* 64 */
#define NBNI (NDIM / 128)      /* 86 */
#define NC16 (NDIM / 16)       /* 688 fragment-column blocks */

// ws layout (bytes)
#define XQ_OFF  0ull
#define WQ_OFF  ((size_t)MDIM * KDIM)                 /* 33554432 */
#define SXT_OFF (WQ_OFF + (size_t)NDIM * KDIM)        /* + 45088768 */
#define SWT_OFF (SXT_OFF + 16ull * MDIM * 4)          /* + 524288 */
#define WS_NEED (SWT_OFF + 16ull * NDIM * 4)          /* ~79.9 MB */

static __device__ __forceinline__ unsigned short f2bf(float f) {
  union { float f; unsigned int u; } v;
  v.f = f;
  unsigned int r = v.u + 0x7FFFu + ((v.u >> 16) & 1u);
  return (unsigned short)(r >> 16);
}

#define GLDS16(g, l) __builtin_amdgcn_global_load_lds(                         \
    (const __attribute__((address_space(1))) void*)(g),                        \
    (__attribute__((address_space(3))) void*)(l), 16, 0, 0)

// ---------------- pass 1 (fused): x -> int8 groups  |  w -> fragment-linear i8
// blocks [0, MDIM): quantize x row (unchanged, verified r8-r10).
// blocks [MDIM, MDIM+NC16): transpose-pack 16 w-columns into MFMA-fragment
// order: wqf[(c16*NTI + kt)*1024 + lane*16] = B[c16*16 + (lane&15)]
//        [kt*64 + (lane>>4)*16 .. +15]  -> GEMM B-loads are contiguous 1KB.
__global__ __launch_bounds__(256) void prep_all(
    const float* __restrict__ x, char* __restrict__ xq, float* __restrict__ sxT,
    const int* __restrict__ qw, const float* __restrict__ scale,
    char* __restrict__ wqf, float* __restrict__ swT) {
  const int t = threadIdx.x;
  if (blockIdx.x < MDIM) {
    const int row = blockIdx.x;
    const float* p = x + (size_t)row * KDIM + t * 16;
    float4v v[4];
#pragma unroll
    for (int c = 0; c < 4; ++c) v[c] = *(const float4v*)(p + c * 4);
    float amax = 0.f;
#pragma unroll
    for (int c = 0; c < 4; ++c)
#pragma unroll
      for (int e = 0; e < 4; ++e) amax = fmaxf(amax, fabsf(v[c][e]));
#pragma unroll
    for (int d = 1; d < 16; d <<= 1) amax = fmaxf(amax, __shfl_xor(amax, d));
    amax = fmaxf(amax, 1e-20f);
    if ((t & 15) == 0)
      sxT[(size_t)(t >> 4) * MDIM + row] = amax * (1.0f / 127.0f);
    const float inv = 127.0f / amax;
    int4v o;
#pragma unroll
    for (int c = 0; c < 4; ++c) {
      unsigned int r = 0;
#pragma unroll
      for (int e = 0; e < 4; ++e) {
        int q = __float2int_rn(v[c][e] * inv);
        r |= ((unsigned int)(q & 255)) << (8 * e);
      }
      o[c] = (int)r;
    }
    *(int4v*)(xq + (size_t)row * KDIM + t * 16) = o;
  } else {
    const int c16 = blockIdx.x - MDIM;       // 0..687
    const int lane = t & 63;
    const int l15 = lane & 15;
    const int lh  = (lane >> 4) & 3;
    const int col = c16 * 16 + l15;
    // inv-scale table: thread t covers (col = c16*16 + t&15, g = t>>4)
    swT[(size_t)(t >> 4) * NDIM + c16 * 16 + (t & 15)] =
        1.0f / scale[(size_t)(c16 * 16 + (t & 15)) * 16 + (t >> 4)];
#pragma unroll
    for (int i = 0; i < 16; ++i) {
      const int kt = i * 4 + (t >> 6);       // 0..63, bijective over (i, t>>6)
      const int* src = qw + (size_t)col * KDIM + kt * 64 + lh * 16;
      int4v v[4];
#pragma unroll
      for (int c = 0; c < 4; ++c) v[c] = *(const int4v*)(src + c * 4);
      int4v o;
#pragma unroll
      for (int c = 0; c < 4; ++c) {
        unsigned int r = 0;
#pragma unroll
        for (int e = 0; e < 4; ++e) r |= ((unsigned int)(v[c][e] & 255)) << (8 * e);
        o[c] = (int)r;
      }
      *(int4v*)(wqf + ((size_t)c16 * NTI + kt) * 1024 + lane * 16) = o;
    }
  }
}

// ---------------- pass 2: 128x128 i8 GEMM; A via LDS, B fragment-linear regs -
// Per tile issue order (pinned): [B-load(t+1) x4 coalesced 1KB, A-stage(t+3)
// x2 GLDS]. Steady vmcnt(8) leaves {A(t+2),B(t+1),A(t+3)}: B budget 1 tile
// (L2-hot), A budget 2 tiles. Tail drains derived FIFO-exactly.
__global__ __launch_bounds__(256, 2) void gemm_i8(
    const char* __restrict__ xq, const char* __restrict__ wqf,
    const float* __restrict__ sxT, const float* __restrict__ swT,
    const float* __restrict__ bias, float* __restrict__ out)
{
  __shared__ unsigned char lds[49152];
  unsigned char* ldsA = lds;              // [4][8192]: 128 rows x 64B
  float* sxl = (float*)(lds + 32768);     // [16][128] row scales
  float* swl = (float*)(lds + 40960);     // [16][128] col inv-scales

  const int t = threadIdx.x;
  const int lane = t & 63;
  const int w = t >> 6;        // wave 0..3
  const int wr = w >> 1;       // 0..1  (A 64-row half)
  const int wc = w & 1;        // 0..1  (B 64-col half)
  const int lh = lane >> 4;    // 0..3
  const int l15 = lane & 15;

  // XCD-bijective swizzle: 5504 = 8 * 688
  const int bid = blockIdx.x;
  const int swz = (bid & 7) * (NBMI * NBNI / 8) + (bid >> 3);
  const int bm = swz / NBNI;
  const int bn = swz % NBNI;

  // A read swizzle: row r holds logical granule g at phys g ^ f(r),
  // f(r) = (r&3)^((r>>2)&3)
  const int f15 = (l15 & 3) ^ (l15 >> 2);
  const int rdGran = (lh ^ f15) << 4;
  // A staging: linear LDS dest (lane*16) <- pre-swizzled global source
  const int srow16 = lane >> 2;
  const int q = (lane & 3) ^ (srow16 & 3) ^ ((srow16 >> 2) & 3);
  const size_t srcOff = (size_t)srow16 * KDIM + q * 16;
  const char* aS = xq + ((size_t)(bm * 128 + w * 32)) * KDIM + srcOff;

  // B fragment-linear: wave (wc) fragment n, tile kt at one contiguous 1KB
  const char* bqf = wqf + ((size_t)(bn * 8 + wc * 4) * NTI) * 1024 + lane * 16;

  // ---- bias: load early and pin (keep it out of the counted vm queue) ----
  float bias_v[4];
#pragma unroll
  for (int n = 0; n < 4; ++n) {
    bias_v[n] = bias[bn * 128 + wc * 64 + n * 16 + l15];
    asm volatile("" :: "v"(bias_v[n]));
  }

  // ---- stage scale tables into LDS ----
  {
    const int tg = t >> 4;
    const int tc = (t & 15) * 8;
    float4v a0 = *(const float4v*)(sxT + (size_t)tg * MDIM + bm * 128 + tc);
    float4v a1 = *(const float4v*)(sxT + (size_t)tg * MDIM + bm * 128 + tc + 4);
    float4v b0 = *(const float4v*)(swT + (size_t)tg * NDIM + bn * 128 + tc);
    float4v b1 = *(const float4v*)(swT + (size_t)tg * NDIM + bn * 128 + tc + 4);
    *(float4v*)(sxl + tg * 128 + tc)     = a0;
    *(float4v*)(sxl + tg * 128 + tc + 4) = a1;
    *(float4v*)(swl + tg * 128 + tc)     = b0;
    *(float4v*)(swl + tg * 128 + tc + 4) = b1;
  }
  __syncthreads();   // drains vmcnt to 0 (compiler emits vmcnt(0) here)

  f32x4 accf[4][4];
  int4v acci[4][4];
#pragma unroll
  for (int m = 0; m < 4; ++m)
#pragma unroll
    for (int n = 0; n < 4; ++n) {
      accf[m][n] = (f32x4){0.f, 0.f, 0.f, 0.f};
      acci[m][n] = (int4v){0, 0, 0, 0};
    }

#define STAGE_A(buf, kt) {                                                     \
  GLDS16(aS + (kt) * BKI,             ldsA + (buf) * 8192 + w * 2048);         \
  GLDS16(aS + 16 * KDIM + (kt) * BKI, ldsA + (buf) * 8192 + w * 2048 + 1024); }

#define BLOAD(BARR, kt) {                                                      \
  _Pragma("unroll")                                                            \
  for (int n = 0; n < 4; ++n)                                                  \
    BARR[n] = *(const int4v*)(bqf + ((size_t)n * NTI + (kt)) * 1024); }

#define RD_A(buf, m) (*(const int4v*)(ldsA + (buf) * 8192 + wr * 4096 +        \
                      (m) * 1024 + l15 * 64 + rdGran))

#define VMW(N) asm volatile("s_waitcnt vmcnt(" N ")" ::: "memory");

// tile t: issue [B(t+1), A(t+3)] (order pinned), ds_read A(t), counted wait,
// 16 MFMA, optional fixup, barrier.
#define TILE(abuf, kt, BCUR, BNXT, DOLOADB, DOSTAGEA, WAITN, DOFIX, DOBAR) {   \
  if (DOLOADB) BLOAD(BNXT, (kt) + 1);                                          \
  __builtin_amdgcn_sched_barrier(0);                                           \
  if (DOSTAGEA) STAGE_A(((abuf) + 3) & 3, (kt) + 3);                           \
  __builtin_amdgcn_sched_barrier(0);                                           \
  int4v a[4];                                                                  \
  _Pragma("unroll")                                                            \
  for (int i = 0; i < 4; ++i) a[i] = RD_A(abuf, i);                            \
  float4v sxv[4]; float swv[4];                                                \
  if (DOFIX) {                                                                 \
    const int g = (kt) >> 2;                                                   \
    _Pragma("unroll")                                                          \
    for (int m = 0; m < 4; ++m)                                                \
      sxv[m] = *(const float4v*)(sxl + g * 128 + wr * 64 + m * 16 + lh * 4);   \
    _Pragma("unroll")                                                          \
    for (int n = 0; n < 4; ++n)                                                \
      swv[n] = swl[g * 128 + wc * 64 + n * 16 + l15];                          \
  }                                                                            \
  VMW(WAITN)                                                                   \
  __builtin_amdgcn_s_setprio(1);                                               \
  _Pragma("unroll")                                                            \
  for (int m = 0; m < 4; ++m)                                                  \
    _Pragma("unroll")                                                          \
    for (int n = 0; n < 4; ++n)                                                \
      acci[m][n] = __builtin_amdgcn_mfma_i32_16x16x64_i8(a[m], BCUR[n],        \
                                                         acci[m][n], 0, 0, 0); \
  __builtin_amdgcn_s_setprio(0);                                               \
  if (DOFIX) {                                                                 \
    _Pragma("unroll")                                                          \
    for (int m = 0; m < 4; ++m)                                                \
      _Pragma("unroll")                                                        \
      for (int n = 0; n < 4; ++n) {                                            \
        _Pragma("unroll")                                                      \
        for (int j = 0; j < 4; ++j)                                            \
          accf[m][n][j] += (float)acci[m][n][j] * (sxv[m][j] * swv[n]);        \
        acci[m][n] = (int4v){0, 0, 0, 0};                                      \
      }                                                                        \
  }                                                                            \
  if (DOBAR) __builtin_amdgcn_s_barrier(); }

  int4v B0f[4], B1f[4];

  // ---- prologue: B(0) [4], A0,A1,A2 staged [6]; drain {B0, A0} -> vmcnt(4) --
  BLOAD(B0f, 0);
  __builtin_amdgcn_sched_barrier(0);
  STAGE_A(0, 0);
  STAGE_A(1, 1);
  STAGE_A(2, 2);
  __builtin_amdgcn_sched_barrier(0);
  VMW("4")                      // leaves A1, A2 in flight
  __builtin_amdgcn_s_barrier();

  for (int kt = 0; kt < NTI - 4; kt += 4) {
    TILE(0, kt,     B0f, B1f, 1, 1, "8", 0, 1)
    TILE(1, kt + 1, B1f, B0f, 1, 1, "8", 0, 1)
    TILE(2, kt + 2, B0f, B1f, 1, 1, "8", 0, 1)
    TILE(3, kt + 3, B1f, B0f, 1, 1, "8", 1, 1)
  }
  // tail: t60 steady; t61 B-only (drain B61: vmcnt(6)); t62 last B (vmcnt(4));
  // t63 drain-all.
  TILE(0, NTI - 4, B0f, B1f, 1, 1, "8", 0, 1)
  TILE(1, NTI - 3, B1f, B0f, 1, 0, "6", 0, 1)
  TILE(2, NTI - 2, B0f, B1f, 1, 0, "4", 0, 1)
  TILE(3, NTI - 1, B1f, B0f, 0, 0, "0", 1, 0)

  // epilogue: bias + fp32 store (C/D map: col=lane&15, row=(lane>>4)*4+j)
#pragma unroll
  for (int m = 0; m < 4; ++m) {
    const int row0 = bm * 128 + wr * 64 + m * 16 + lh * 4;
#pragma unroll
    for (int n = 0; n < 4; ++n) {
      const int col = bn * 128 + wc * 64 + n * 16 + l15;
      const float bv_ = bias_v[n];
#pragma unroll
      for (int j = 0; j < 4; ++j)
        out[(size_t)(row0 + j) * NDIM + col] = accf[m][n][j] + bv_;
    }
  }
#undef TILE
#undef VMW
#undef RD_A
#undef BLOAD
#undef STAGE_A
}

// ---------------- fallback: fused single-pass (round-1 kernel) ----------------
__global__ __launch_bounds__(256, 2) void clinear_fused(
    const float* __restrict__ x,
    const int* __restrict__ qw,
    const float* __restrict__ scale,
    const float* __restrict__ bias,
    float* __restrict__ out)
{
  __shared__ unsigned char ldsA[128 * 64 * 2];
  __shared__ unsigned char ldsB[128 * 64 * 2];

  const int t = threadIdx.x;
  const int lane = t & 63;
  const int wave = t >> 6;
  const int wr = wave >> 1;
  const int wc = wave & 1;

  const int NBN = NDIM / 128;
  const int bid = blockIdx.x;
  const int cpx = ((MDIM / 128) * NBN) >> 3;
  const int swz = (bid & 7) * cpx + (bid >> 3);
  const int bm = swz / NBN;
  const int bn = swz % NBN;

  const int srow = t >> 1;
  const int shalf = t & 1;
  const float* aptr = x  + (size_t)(bm * 128 + srow) * KDIM + shalf * 32;
  const int*   bptr = qw + (size_t)(bn * 128 + srow) * KDIM + shalf * 32;
  const float* sptr = scale + (size_t)(bn * 128 + srow) * (KDIM / 256);
  const int arx = srow & 7;

  f32x4 acc[4][4];
#pragma unroll
  for (int i = 0; i < 4; ++i)
#pragma unroll
    for (int j = 0; j < 4; ++j)
      acc[i][j] = (f32x4){0.f, 0.f, 0.f, 0.f};

  float bias_v[4];
#pragma unroll
  for (int n = 0; n < 4; ++n)
    bias_v[n] = bias[bn * 128 + wc * 64 + n * 16 + (lane & 15)];

  for (int kt = 0; kt < KDIM / 64; ++kt) {
    const int k0 = kt * 64;
    float4v av[8];
    int4v   bv[8];
#pragma unroll
    for (int j = 0; j < 8; ++j) av[j] = *(const float4v*)(aptr + k0 + 4 * j);
#pragma unroll
    for (int j = 0; j < 8; ++j) bv[j] = *(const int4v*)(bptr + k0 + 4 * j);
    const float inv = 1.0f / sptr[k0 >> 8];

    __syncthreads();
#pragma unroll
    for (int c = 0; c < 4; ++c) {
      short8 pa, pb;
#pragma unroll
      for (int e = 0; e < 8; ++e) {
        const int v = c * 8 + e;
        pa[e] = (short)f2bf(av[v >> 2][v & 3]);
        pb[e] = (short)f2bf((float)bv[v >> 2][v & 3] * inv);
      }
      const int cc = shalf * 4 + c;
      *(short8*)(ldsA + srow * 128 + ((cc ^ arx) << 4)) = pa;
      *(short8*)(ldsB + srow * 128 + ((cc ^ arx) << 4)) = pb;
    }
    __syncthreads();

    short8 af[4][2], bfr[4][2];
#pragma unroll
    for (int m = 0; m < 4; ++m) {
      const int r = wr * 64 + m * 16 + (lane & 15);
      const int rx = r & 7;
#pragma unroll
      for (int ks = 0; ks < 2; ++ks) {
        const int ch = ks * 4 + (lane >> 4);
        af[m][ks] = *(const short8*)(ldsA + r * 128 + ((ch ^ rx) << 4));
      }
    }
#pragma unroll
    for (int n = 0; n < 4; ++n) {
      const int r = wc * 64 + n * 16 + (lane & 15);
      const int rx = r & 7;
#pragma unroll
      for (int ks = 0; ks < 2; ++ks) {
        const int ch = ks * 4 + (lane >> 4);
        bfr[n][ks] = *(const short8*)(ldsB + r * 128 + ((ch ^ rx) << 4));
      }
    }
#pragma unroll
    for (int ks = 0; ks < 2; ++ks)
#pragma unroll
      for (int m = 0; m < 4; ++m)
#pragma unroll
        for (int n = 0; n < 4; ++n)
          acc[m][n] = __builtin_amdgcn_mfma_f32_16x16x32_bf16(
              af[m][ks], bfr[n][ks], acc[m][n], 0, 0, 0);
  }

#pragma unroll
  for (int m = 0; m < 4; ++m) {
    const int row0 = bm * 128 + wr * 64 + m * 16 + (lane >> 4) * 4;
#pragma unroll
    for (int n = 0; n < 4; ++n) {
      const int col = bn * 128 + wc * 64 + n * 16 + (lane & 15);
      const float bv_ = bias_v[n];
#pragma unroll
      for (int j = 0; j < 4; ++j)
        out[(size_t)(row0 + j) * NDIM + col] = acc[m][n][j] + bv_;
    }
  }
}

extern "C" void kernel_launch(void* const* d_in, const int* in_sizes, int n_in,
                              void* d_out, int out_size, void* d_ws, size_t ws_size,
                              hipStream_t stream) {
  const float* x     = (const float*)d_in[0];
  const int*   qw    = (const int*)d_in[1];
  const float* scale = (const float*)d_in[2];
  const float* bias  = (const float*)d_in[3];
  float* out = (float*)d_out;

  if (ws_size >= WS_NEED) {
    char*  xqb = (char*)d_ws + XQ_OFF;
    char*  wqf = (char*)d_ws + WQ_OFF;
    float* sxT = (float*)((char*)d_ws + SXT_OFF);
    float* swT = (float*)((char*)d_ws + SWT_OFF);
    hipLaunchKernelGGL(prep_all, dim3(MDIM + NC16), dim3(256), 0, stream,
                       x, xqb, sxT, qw, scale, wqf, swT);
    hipLaunchKernelGGL(gemm_i8, dim3(NBMI * NBNI), dim3(256), 0, stream,
                       xqb, wqf, sxT, swT, bias, out);
  } else {
    hipLaunchKernelGGL(clinear_fused, dim3((MDIM / 128) * (NDIM / 128)), dim3(256),
                       0, stream, x, qw, scale, bias, out);
  }
}